// Round 1
// baseline (5171.082 us; speedup 1.0000x reference)
//
#include <hip/hip_runtime.h>

#define B_ 64
#define T_ 2048
#define F_ 8
#define H_ 128

typedef _Float16 v2h __attribute__((ext_vector_type(2)));

// pack two fp32 into one dword of two f16 (RTN via cast)
__device__ __forceinline__ unsigned pk2h(float lo, float hi) {
    v2h p;
    p[0] = (_Float16)lo;
    p[1] = (_Float16)hi;
    return __builtin_bit_cast(unsigned, p);
}

#if __has_builtin(__builtin_amdgcn_fdot2)
__device__ __forceinline__ float fdot2a(unsigned a, unsigned b, float c) {
    return __builtin_amdgcn_fdot2(__builtin_bit_cast(v2h, a),
                                  __builtin_bit_cast(v2h, b), c, false);
}
#else
__device__ __forceinline__ float fdot2a(unsigned a, unsigned b, float c) {
    v2h av = __builtin_bit_cast(v2h, a);
    v2h bv = __builtin_bit_cast(v2h, b);
    c += (float)av[0] * (float)bv[0];
    c += (float)av[1] * (float)bv[1];
    return c;
}
#endif

__device__ __forceinline__ float sigm(float x) {
    return 1.0f / (1.0f + __expf(-x));
}
__device__ __forceinline__ float tanh_f(float x) {
    float e = __expf(2.0f * x);
    return 1.0f - 2.0f / (e + 1.0f);
}

// lane ^ 1 and lane ^ 2 within quads: DPP quad_perm (VALU pipe, cheap).
// lane ^ 4: ds_swizzle xor mode (crosses quad boundary).
#if __has_builtin(__builtin_amdgcn_mov_dpp)
template <int CTRL>
__device__ __forceinline__ float qperm(float v) {
    int i = __builtin_bit_cast(int, v);
    i = __builtin_amdgcn_mov_dpp(i, CTRL, 0xF, 0xF, true);
    return __builtin_bit_cast(float, i);
}
__device__ __forceinline__ float lane_xor1(float v) { return qperm<0xB1>(v); } // [1,0,3,2]
__device__ __forceinline__ float lane_xor2(float v) { return qperm<0x4E>(v); } // [2,3,0,1]
#else
__device__ __forceinline__ float lane_xor1(float v) {
    int i = __builtin_amdgcn_ds_swizzle(__builtin_bit_cast(int, v), 0x041F);
    return __builtin_bit_cast(float, i);
}
__device__ __forceinline__ float lane_xor2(float v) {
    int i = __builtin_amdgcn_ds_swizzle(__builtin_bit_cast(int, v), 0x081F);
    return __builtin_bit_cast(float, i);
}
#endif
__device__ __forceinline__ float lane_xor4(float v) {
    int i = __builtin_amdgcn_ds_swizzle(__builtin_bit_cast(int, v), 0x101F);
    return __builtin_bit_cast(float, i);
}

// Thread map (1024 threads): tid = h_idx*8 + gslot*2 + half
//   h_idx 0..127, gslot 0..3 -> gate order [i, g, f, o] (rows {0,2,1,3}*128 + h_idx),
//   half 0..1 -> which 64-element half of the dot product this thread accumulates.
// Per 8-lane group the full i,f,g,o set is resident -> cell update fully in-register:
//   a   (activated own gate):      lanes 01:i  23:g  45:f  67:o
//   s1 = xor2(a):                  lanes 01:g  23:i  45:o  67:f
//   p  = sub<4 ? a*s1 : f*c       (f = a on 45, s1 on 67)
//   c' = p + xor4(p)  == i*g + f*c   (replicated, all 8 lanes)
//   h  = o * tanh(c'), o = s1 on 45, a on 67; lane sub==4 writes h (f16) to LDS.
__global__ __launch_bounds__(1024, 4)
void lstm2_pipe_kernel(const float* __restrict__ x,
                       const float* __restrict__ wih0,
                       const float* __restrict__ whh0,
                       const float* __restrict__ bih0,
                       const float* __restrict__ bhh0,
                       const float* __restrict__ wih1,
                       const float* __restrict__ whh1,
                       const float* __restrict__ bih1,
                       const float* __restrict__ bhh1,
                       const float* __restrict__ wlin,
                       const float* __restrict__ blin,
                       float* __restrict__ out)
{
    __shared__ __align__(16) unsigned x_lds[T_ * F_ / 2];   // 32 KB packed f16 x
    __shared__ __align__(16) unsigned h0_p[2][H_ / 2];      // double-buffered h0 (f16 pairs)
    __shared__ __align__(16) unsigned h1_p[2][H_ / 2];      // double-buffered h1
    __shared__ __align__(16) unsigned wlin_p[512];          // w_lin packed f16 pairs
    __shared__ float blin_f[F_];

    const int tid   = threadIdx.x;
    const int b     = blockIdx.x;
    const int h_idx = tid >> 3;
    const int sub   = tid & 7;
    const int gslot = sub >> 1;
    const int half  = sub & 1;
    const int grow  = (0x3120 >> (gslot * 4)) & 0xF;   // {0,2,1,3}[gslot]
    const int row   = grow * H_ + h_idx;               // gate row in PyTorch i,f,g,o layout

    // ---- stage x[b] into LDS as packed f16 pairs ----
    const float4* xp = (const float4*)(x + (size_t)b * T_ * F_);
    #pragma unroll
    for (int i = 0; i < 4; ++i) {
        int idx = tid + i * 1024;          // 4096 float4 total
        float4 v = xp[idx];
        x_lds[idx * 2 + 0] = pk2h(v.x, v.y);
        x_lds[idx * 2 + 1] = pk2h(v.z, v.w);
    }

    // ---- per-thread half-row weights -> VGPRs (98 packed dwords) ----
    unsigned rwih0[2];
    {
        const float4* p = (const float4*)(wih0 + (size_t)row * F_ + half * 4);
        float4 v = p[0];
        rwih0[0] = pk2h(v.x, v.y);
        rwih0[1] = pk2h(v.z, v.w);
    }
    unsigned rwhh0[32], rwih1[32], rwhh1[32];
    {
        const float4* p = (const float4*)(whh0 + (size_t)row * H_ + half * 64);
        #pragma unroll
        for (int i = 0; i < 16; ++i) {
            float4 v = p[i];
            rwhh0[i * 2 + 0] = pk2h(v.x, v.y);
            rwhh0[i * 2 + 1] = pk2h(v.z, v.w);
        }
    }
    {
        const float4* p = (const float4*)(wih1 + (size_t)row * H_ + half * 64);
        #pragma unroll
        for (int i = 0; i < 16; ++i) {
            float4 v = p[i];
            rwih1[i * 2 + 0] = pk2h(v.x, v.y);
            rwih1[i * 2 + 1] = pk2h(v.z, v.w);
        }
    }
    {
        const float4* p = (const float4*)(whh1 + (size_t)row * H_ + half * 64);
        #pragma unroll
        for (int i = 0; i < 16; ++i) {
            float4 v = p[i];
            rwhh1[i * 2 + 0] = pk2h(v.x, v.y);
            rwhh1[i * 2 + 1] = pk2h(v.z, v.w);
        }
    }
    const float bias0 = bih0[row] + bhh0[row];
    const float bias1 = bih1[row] + bhh1[row];

    if (tid < 512) {
        float2 v = ((const float2*)wlin)[tid];
        wlin_p[tid] = pk2h(v.x, v.y);
    }
    if (tid < F_) blin_f[tid] = blin[tid];
    if (tid < H_ / 2) {
        h0_p[0][tid] = 0u; h0_p[1][tid] = 0u;
        h1_p[0][tid] = 0u; h1_p[1][tid] = 0u;
    }
    __syncthreads();

    const bool is_g = (gslot == 1);
    const bool lo4  = (sub < 4);
    const bool lt6  = (sub < 6);
    float c0 = 0.0f, c1 = 0.0f;    // cell state, replicated across each 8-lane group

    // Pipelined: tick k does L0(t=k) || L1(t=k-1) || OUT(t=k-2). ONE barrier per tick.
    for (int k = 0; k <= T_ + 1; ++k) {
        const int rb = (k + 1) & 1;   // buffer holding h0(k-1); write parity for h1(k-1)
        const int wb = k & 1;         // write parity for h0(k); buffer holding h1(k-2)

        // ---------- layer 0: t = k ----------
        if (k < T_) {
            float aa = 0.0f, ab = 0.0f;
            uint2 xv = *(const uint2*)&x_lds[k * 4 + half * 2];
            aa = fdot2a(rwih0[0], xv.x, aa);
            ab = fdot2a(rwih0[1], xv.y, ab);
            const unsigned* hr = &h0_p[rb][half * 32];
            #pragma unroll
            for (int j = 0; j < 8; ++j) {
                uint4 hv = *(const uint4*)&hr[j * 4];
                aa = fdot2a(rwhh0[j * 4 + 0], hv.x, aa);
                ab = fdot2a(rwhh0[j * 4 + 1], hv.y, ab);
                aa = fdot2a(rwhh0[j * 4 + 2], hv.z, aa);
                ab = fdot2a(rwhh0[j * 4 + 3], hv.w, ab);
            }
            float a = aa + ab;
            a += lane_xor1(a);            // combine halves: both lanes get full row sum
            a += bias0;
            float xin = is_g ? 2.0f * a : a;
            float s   = sigm(xin);
            float act = is_g ? 2.0f * s - 1.0f : s;   // tanh via sigmoid, no divergence
            float s1  = lane_xor2(act);
            float p   = lo4 ? act * s1 : (lt6 ? act : s1) * c0;
            float cn  = p + lane_xor4(p);
            c0 = cn;
            float oval = lt6 ? s1 : act;
            float h = oval * tanh_f(cn);
            if (sub == 4) ((_Float16*)&h0_p[wb][0])[h_idx] = (_Float16)h;
        }

        // ---------- layer 1: t = k-1 ----------
        if (k >= 1 && k <= T_) {
            float aa = 0.0f, ab = 0.0f;
            const unsigned* h0r = &h0_p[rb][half * 32];   // h0(k-1)
            const unsigned* h1r = &h1_p[wb][half * 32];   // h1(k-2)
            #pragma unroll
            for (int j = 0; j < 8; ++j) {
                uint4 hv = *(const uint4*)&h0r[j * 4];
                aa = fdot2a(rwih1[j * 4 + 0], hv.x, aa);
                ab = fdot2a(rwih1[j * 4 + 1], hv.y, ab);
                aa = fdot2a(rwih1[j * 4 + 2], hv.z, aa);
                ab = fdot2a(rwih1[j * 4 + 3], hv.w, ab);
            }
            #pragma unroll
            for (int j = 0; j < 8; ++j) {
                uint4 hv = *(const uint4*)&h1r[j * 4];
                aa = fdot2a(rwhh1[j * 4 + 0], hv.x, aa);
                ab = fdot2a(rwhh1[j * 4 + 1], hv.y, ab);
                aa = fdot2a(rwhh1[j * 4 + 2], hv.z, aa);
                ab = fdot2a(rwhh1[j * 4 + 3], hv.w, ab);
            }
            float a = aa + ab;
            a += lane_xor1(a);
            a += bias1;
            float xin = is_g ? 2.0f * a : a;
            float s   = sigm(xin);
            float act = is_g ? 2.0f * s - 1.0f : s;
            float s1  = lane_xor2(act);
            float p   = lo4 ? act * s1 : (lt6 ? act : s1) * c1;
            float cn  = p + lane_xor4(p);
            c1 = cn;
            float oval = lt6 ? s1 : act;
            float h = oval * tanh_f(cn);
            if (sub == 4) ((_Float16*)&h1_p[rb][0])[h_idx] = (_Float16)h;   // h1(k-1)
        }

        // ---------- output linear: t = k-2 (wave 0 only) ----------
        if (k >= 2 && tid < 64) {
            int fo = tid >> 3;       // output feature 0..7
            int l  = tid & 7;        // 8 lanes per feature, 16 h-elems each
            const unsigned* hp = &h1_p[wb][0];   // h1(k-2)
            float a = 0.0f;
            #pragma unroll
            for (int jj = 0; jj < 8; ++jj) {
                a = fdot2a(wlin_p[fo * 64 + l * 8 + jj], hp[l * 8 + jj], a);
            }
            a += __shfl_down(a, 4, 8);
            a += __shfl_down(a, 2, 8);
            a += __shfl_down(a, 1, 8);
            if (l == 0) {
                out[((size_t)b * T_ + (k - 2)) * F_ + fo] = a + blin_f[fo];
            }
        }

        __syncthreads();
    }
}

extern "C" void kernel_launch(void* const* d_in, const int* in_sizes, int n_in,
                              void* d_out, int out_size, void* d_ws, size_t ws_size,
                              hipStream_t stream) {
    const float* x    = (const float*)d_in[0];
    const float* wih0 = (const float*)d_in[1];
    const float* whh0 = (const float*)d_in[2];
    const float* bih0 = (const float*)d_in[3];
    const float* bhh0 = (const float*)d_in[4];
    const float* wih1 = (const float*)d_in[5];
    const float* whh1 = (const float*)d_in[6];
    const float* bih1 = (const float*)d_in[7];
    const float* bhh1 = (const float*)d_in[8];
    const float* wlin = (const float*)d_in[9];
    const float* blin = (const float*)d_in[10];
    float* out = (float*)d_out;

    lstm2_pipe_kernel<<<dim3(B_), dim3(1024), 0, stream>>>(
        x, wih0, whh0, bih0, bhh0, wih1, whh1, bih1, bhh1, wlin, blin, out);
}